// Round 7
// baseline (276.777 us; speedup 1.0000x reference)
//
#include <hip/hip_runtime.h>
#include <stdint.h>

#define NB 32
#define NS 8192
#define ND 128
#define KTOP 4096
#define NCLUST 1024
#define CIN 512
#define HIDN 256
#define NMEM 128
#define NCLS 10
#define HALFCNT 4194304u   // (NB*NCLUST*HIDN)/2

typedef unsigned long long ull;
typedef __attribute__((ext_vector_type(8))) short bf16x8;
typedef __attribute__((ext_vector_type(4))) float f32x4;

// ---------------- threefry2x32-20, JAX-exact, key = (0, 1234) ----------------
__device__ __forceinline__ unsigned int rotl32(unsigned int v, int r) {
  return (v << r) | (v >> (32 - r));
}

__device__ __forceinline__ void threefry_block(unsigned int& x0, unsigned int& x1) {
  const unsigned int k0 = 0u;
  const unsigned int k1 = 1234u;
  const unsigned int k2 = 0x1BD11BDAu ^ 0u ^ 1234u;
  x0 += k0; x1 += k1;
#define TF_R(r) { x0 += x1; x1 = rotl32(x1, (r)); x1 ^= x0; }
  TF_R(13) TF_R(15) TF_R(26) TF_R(6)   x0 += k1; x1 += k2 + 1u;
  TF_R(17) TF_R(29) TF_R(16) TF_R(24)  x0 += k2; x1 += k0 + 2u;
  TF_R(13) TF_R(15) TF_R(26) TF_R(6)   x0 += k0; x1 += k1 + 3u;
  TF_R(17) TF_R(29) TF_R(16) TF_R(24)  x0 += k1; x1 += k2 + 4u;
  TF_R(13) TF_R(15) TF_R(26) TF_R(6)   x0 += k2; x1 += k0 + 5u;
#undef TF_R
}

__device__ __forceinline__ unsigned int f2bf(float f) {
  unsigned int u = __float_as_uint(f);
  return (u + 0x7fffu + ((u >> 16) & 1u)) >> 16;
}
__device__ __forceinline__ unsigned int pack2bf(float lo, float hi) {
  return f2bf(lo) | (f2bf(hi) << 16);
}

__device__ __forceinline__ void gload_lds16(const void* g, void* l) {
  __builtin_amdgcn_global_load_lds(
      (const __attribute__((address_space(1))) unsigned int*)g,
      (__attribute__((address_space(3))) unsigned int*)l, 16, 0, 0);
}

__device__ __forceinline__ ull shfl_xor_u64(ull x, int m) {
  unsigned int lo = (unsigned int)x, hi = (unsigned int)(x >> 32);
  lo = (unsigned int)__shfl_xor((int)lo, m);
  hi = (unsigned int)__shfl_xor((int)hi, m);
  return ((ull)hi << 32) | lo;
}

// -- kernel 1: token norms -> keys; zero xc; W_fc->bf16; bernoulli mask gen --
#define NORM_BLOCKS 32768
#define WPREP_BLOCKS 64
#define MASK_BLOCKS 16384   // 16384 blocks x 4 waves -> 65536 word-pairs
__global__ __launch_bounds__(256) void norms_kernel(
    const float* __restrict__ x, ull* __restrict__ keys,
    float* __restrict__ xc, const float* __restrict__ Wfc,
    unsigned short* __restrict__ Wbf, ull* __restrict__ maskw) {
  const int blk = blockIdx.x;
  if (blk >= NORM_BLOCKS + WPREP_BLOCKS) {
    // --- deterministic bernoulli mask: one wave -> words (W, W+65536) ---
    const int blkm = blk - (NORM_BLOCKS + WPREP_BLOCKS);
    const int wv = threadIdx.x >> 6, lane = threadIdx.x & 63;
    const unsigned int W = (unsigned int)(blkm * 4 + wv);   // [0, 65536)
    unsigned int a = W * 64u + (unsigned int)lane;          // flat (low half)
    unsigned int b2 = a + HALFCNT;
    threefry_block(a, b2);
    const ull m0 = __ballot((a & 0x80000000u) == 0u);
    const ull m1 = __ballot((b2 & 0x80000000u) == 0u);
    if (lane == 0) {
      maskw[W] = m0;
      maskw[W + 65536u] = m1;
    }
    return;
  }
  if (blk >= NORM_BLOCKS) {
    // --- W_fc f32 -> bf16, same [256][512] layout ---
    const int t = (blk - NORM_BLOCKS) * 256 + threadIdx.x;
    const float4* s = (const float4*)(Wfc + (size_t)t * 8);
    const float4 a = s[0], b = s[1];
    uint4 o;
    o.x = pack2bf(a.x, a.y); o.y = pack2bf(a.z, a.w);
    o.z = pack2bf(b.x, b.y); o.w = pack2bf(b.z, b.w);
    *(uint4*)(Wbf + (size_t)t * 8) = o;
    return;
  }
  const int t = blk * 256 + threadIdx.x;
  if (t < NB * HIDN) xc[t] = 0.0f;
  const int token = t >> 5;
  const int l = t & 31;
  const float4 v = ((const float4*)(x + (size_t)token * ND))[l];
  float ss = v.x * v.x + v.y * v.y + v.z * v.z + v.w * v.w;
#pragma unroll
  for (int off = 16; off >= 1; off >>= 1) ss += __shfl_xor(ss, off);
  if (l == 0) {
    const float nrm = sqrtf(ss);
    const unsigned int ub = ~__float_as_uint(nrm);
    keys[token] = ((ull)ub << 32) | (unsigned int)(token & (NS - 1));
  }
}

// ---- kernel 2a: per-half bitonic sort (4096 elems, asc for half 0, desc 1) --
#define CMPEX(J, K, HF)                                                 \
  {                                                                     \
    _Pragma("unroll") for (int r = 0; r < 8; ++r) {                     \
      if ((r & (J)) == 0) {                                             \
        const int i0 = (tid << 3) + r;                                  \
        const bool up2 = (((i0 & (K)) == 0) != (HF));                   \
        const ull lo = v[r], hi = v[r | (J)];                           \
        const ull mn = lo < hi ? lo : hi;                               \
        const ull mx = lo < hi ? hi : lo;                               \
        v[r] = up2 ? mn : mx;                                           \
        v[r | (J)] = up2 ? mx : mn;                                     \
      }                                                                 \
    }                                                                   \
  }

__global__ __launch_bounds__(512) void sortA_kernel(ull* __restrict__ keys) {
  __shared__ ull slds[8 * 512];          // 32 KiB, transposed [r][tid]
  const int b = blockIdx.x >> 1;
  const int half = blockIdx.x & 1;
  const bool hf = (half != 0);
  const int tid = threadIdx.x;
  ull v[8];
  ull* base = keys + (size_t)b * NS + half * 4096;
#pragma unroll
  for (int r = 0; r < 8; ++r) v[r] = base[tid * 8 + r];

  for (int k = 2; k <= 4096; k <<= 1) {
    // cross-wave rounds via LDS (j = 512..2048)
    for (int j = k >> 1; j >= 512; j >>= 1) {
      __syncthreads();
#pragma unroll
      for (int r = 0; r < 8; ++r) slds[r * 512 + tid] = v[r];
      __syncthreads();
      const int ptid = tid ^ (j >> 3);
      const bool up2 = ((((tid << 3) & k) == 0) != hf);
      const bool lower = (((tid << 3) & j) == 0);
      const bool keepmin = (up2 == lower);
#pragma unroll
      for (int r = 0; r < 8; ++r) {
        const ull p = slds[r * 512 + ptid];
        const ull mn = v[r] < p ? v[r] : p;
        const ull mx = v[r] < p ? p : v[r];
        v[r] = keepmin ? mn : mx;
      }
    }
    // intra-wave rounds via shfl (j = 8..256)
    {
      const int jstart = (k >> 1) < 256 ? (k >> 1) : 256;
      for (int j = jstart; j >= 8; j >>= 1) {
        const int lanemask = j >> 3;
        const bool up2 = ((((tid << 3) & k) == 0) != hf);
        const bool lower = (((tid << 3) & j) == 0);
        const bool keepmin = (up2 == lower);
#pragma unroll
        for (int r = 0; r < 8; ++r) {
          const ull p = shfl_xor_u64(v[r], lanemask);
          const ull mn = v[r] < p ? v[r] : p;
          const ull mx = v[r] < p ? p : v[r];
          v[r] = keepmin ? mn : mx;
        }
      }
    }
    // in-register rounds (j = 4,2,1)
    if (k >= 8)      { CMPEX(4, k, hf) CMPEX(2, k, hf) CMPEX(1, k, hf) }
    else if (k == 4) { CMPEX(2, k, hf) CMPEX(1, k, hf) }
    else             { CMPEX(1, k, hf) }
  }

#pragma unroll
  for (int r = 0; r < 8; ++r) base[tid * 8 + r] = v[r];
}

// ---- kernel 2b: merge asc-half + desc-half, keep top 4096 (lower), sorted ---
__global__ __launch_bounds__(512) void sortB_kernel(
    const ull* __restrict__ keys, unsigned int* __restrict__ topk) {
  __shared__ ull slds[8 * 512];          // 32 KiB (lower half only)
  const int b = blockIdx.x;
  const int tid = threadIdx.x;
  ull v[8];
  const ull* base = keys + (size_t)b * NS;
#pragma unroll
  for (int r = 0; r < 8; ++r) v[r] = base[tid * 8 + r];
  // j = 4096 round: partner of i is i+4096 -> pure per-thread min
#pragma unroll
  for (int r = 0; r < 8; ++r) {
    const ull u = base[4096 + tid * 8 + r];
    v[r] = v[r] < u ? v[r] : u;
  }
  // bitonic-merge lower half: j = 2048,1024,512 via LDS
  for (int j = 2048; j >= 512; j >>= 1) {
    __syncthreads();
#pragma unroll
    for (int r = 0; r < 8; ++r) slds[r * 512 + tid] = v[r];
    __syncthreads();
    const int ptid = tid ^ (j >> 3);
    const bool keepmin = (((tid << 3) & j) == 0);
#pragma unroll
    for (int r = 0; r < 8; ++r) {
      const ull p = slds[r * 512 + ptid];
      const ull mn = v[r] < p ? v[r] : p;
      const ull mx = v[r] < p ? p : v[r];
      v[r] = keepmin ? mn : mx;
    }
  }
  // j = 256..8 via shfl
  for (int j = 256; j >= 8; j >>= 1) {
    const int lanemask = j >> 3;
    const bool keepmin = (((tid << 3) & j) == 0);
#pragma unroll
    for (int r = 0; r < 8; ++r) {
      const ull p = shfl_xor_u64(v[r], lanemask);
      const ull mn = v[r] < p ? v[r] : p;
      const ull mx = v[r] < p ? p : v[r];
      v[r] = keepmin ? mn : mx;
    }
  }
  // j = 4,2,1 in registers (ascending merge: up2 always true)
  CMPEX(4, 8192, false) CMPEX(2, 8192, false) CMPEX(1, 8192, false)
#pragma unroll
  for (int r = 0; r < 8; ++r)
    topk[b * KTOP + tid * 8 + r] = (unsigned int)v[r];
}

// ------ kernel 3: gather + bf16 MFMA GEMM + bias + mask + relu + col-sum ----
// 1024 blocks x 256 threads (4 waves). Tile: 32 rows x 256 cols, BK=64.
// Little's-law fix: ALL 16 A-gather float4 loads issued upfront (256 B/thread
// in flight) -> gather is BW-bound, not latency-bound. Mask bits precomputed.
__global__ __launch_bounds__(256, 4) void gemm_kernel(
    const float* __restrict__ x, const unsigned short* __restrict__ Wbf,
    const float* __restrict__ bfc, const unsigned int* __restrict__ topk,
    const ull* __restrict__ maskw, float* __restrict__ xc) {
  __shared__ __align__(16) unsigned short Al[32 * 64];    // 4 KiB, swizzled
  __shared__ __align__(16) unsigned short Bl[256 * 64];   // 32 KiB, swizzled
  __shared__ int tokL[128];   // [row 0..31][slot 0..3]

  const int bid = blockIdx.x;            // 1024 = 32 batches x 32 m-tiles
  const int bb = bid >> 5;               // batch
  const int m0c = (bid & 31) * 32;       // cluster base
  const int t = threadIdx.x;
  const int w = t >> 6, l = t & 63;      // wave w owns cols [w*64, w*64+64)
  const int lrow = l & 15, lk = l >> 4;

  if (t < 128)
    tokL[t] = (int)topk[bb * KTOP + (m0c + (t >> 2)) * 4 + (t & 3)];
  __syncthreads();

  // --- upfront A-gather: thread (arow, kq) loads its entire K-consumption ---
  const int arow = t >> 3, kq = t & 7;
  float4 ar[16];
  {
    const float* xb = x + (size_t)bb * NS * ND;
#pragma unroll
    for (int kt = 0; kt < 8; ++kt) {
      const int cs = kt * 8 + kq;
      const int token = tokL[arow * 4 + (cs >> 4)];
      const float* asrc = xb + (size_t)token * ND + (cs & 15) * 8;
      ar[kt * 2]     = ((const float4*)asrc)[0];
      ar[kt * 2 + 1] = ((const float4*)asrc)[1];
    }
  }

  f32x4 acc[2][4];
#pragma unroll
  for (int m = 0; m < 2; ++m)
#pragma unroll
    for (int n = 0; n < 4; ++n) acc[m][n] = (f32x4)0.f;

  // per-lane source swizzle for B staging (linear LDS dest, swizzled source)
  const int brow_in8 = l >> 3;
  const int bkb_src = ((l & 7) * 16) ^ (brow_in8 << 4);

  for (int kt = 0; kt < 8; ++kt) {
    // write A regs (chunk kt) to swizzled LDS: 1 uint4 per thread
    {
      const float4 a0 = ar[kt * 2], a1 = ar[kt * 2 + 1];
      uint4 p0;
      p0.x = pack2bf(a0.x, a0.y); p0.y = pack2bf(a0.z, a0.w);
      p0.z = pack2bf(a1.x, a1.y); p0.w = pack2bf(a1.z, a1.w);
      const int swz = (arow & 7) << 4;
      *(uint4*)((char*)Al + arow * 128 + ((kq * 16) ^ swz)) = p0;
    }
    // stage B (bf16): 256 rows x 128 B = 32 groups of 1 KiB; wave w: 8 groups
    {
#pragma unroll
      for (int q = 0; q < 8; ++q) {
        const int grp = w * 8 + q;
        const int row = grp * 8 + brow_in8;
        const char* g = (const char*)Wbf + (size_t)row * 1024 + kt * 128 +
                        bkb_src;
        gload_lds16(g, (char*)Bl + grp * 1024);
      }
    }
    __syncthreads();   // A + B tiles ready

    // compute: 2 kk-steps x 8 MFMA per wave
    const int swz = (lrow & 7) << 4;
#pragma unroll
    for (int kk = 0; kk < 2; ++kk) {
      const int koff = (kk * 64 + lk * 16) ^ swz;
      bf16x8 af[2], bfr[4];
#pragma unroll
      for (int m = 0; m < 2; ++m)
        af[m] = *(const bf16x8*)((const char*)Al +
                                 (m * 16 + lrow) * 128 + koff);
#pragma unroll
      for (int n = 0; n < 4; ++n)
        bfr[n] = *(const bf16x8*)((const char*)Bl +
                                  (w * 64 + n * 16 + lrow) * 128 + koff);
#pragma unroll
      for (int m = 0; m < 2; ++m)
#pragma unroll
        for (int n = 0; n < 4; ++n)
          acc[m][n] = __builtin_amdgcn_mfma_f32_16x16x32_bf16(
              af[m], bfr[n], acc[m][n], 0, 0, 0);
    }
    __syncthreads();   // LDS consumed; safe to overwrite next iter
  }

  // --- epilogue: bias + precomputed mask + relu + column partials ---
  float bias_n[4];
#pragma unroll
  for (int n = 0; n < 4; ++n) bias_n[n] = bfc[w * 64 + n * 16 + lrow];

  // mask words: one u64 covers cols [w*64, w*64+64) of one row
  ull mw[2][4];
#pragma unroll
  for (int m = 0; m < 2; ++m)
#pragma unroll
    for (int reg = 0; reg < 4; ++reg) {
      const int row = m0c + m * 16 + lk * 4 + reg;
      mw[m][reg] = maskw[(size_t)(bb * NCLUST + row) * 4 + w];
    }

  float csum[4] = {0.f, 0.f, 0.f, 0.f};
#pragma unroll
  for (int n = 0; n < 4; ++n) {
    const int bit = n * 16 + lrow;
#pragma unroll
    for (int m = 0; m < 2; ++m) {
#pragma unroll
      for (int reg = 0; reg < 4; ++reg) {
        const bool keep = ((mw[m][reg] >> bit) & 1ull) != 0ull;
        float vv = acc[m][n][reg] + bias_n[n];
        vv = keep ? fmaxf(vv, 0.0f) : 0.0f;
        csum[n] += vv;
      }
    }
  }
  // reduce across lk groups within wave; waves own disjoint cols
#pragma unroll
  for (int n = 0; n < 4; ++n) {
    csum[n] += __shfl_xor(csum[n], 16);
    csum[n] += __shfl_xor(csum[n], 32);
  }
  if (l < 16) {
#pragma unroll
    for (int n = 0; n < 4; ++n)
      atomicAdd(&xc[bb * HIDN + w * 64 + n * 16 + l], csum[n]);
  }
}

// ---------------- kernel 4: mean + memory MLP + output head ----------------
__global__ __launch_bounds__(128) void tail_kernel(
    const float* __restrict__ xc, const float* __restrict__ memory,
    const float* __restrict__ Wmem, const float* __restrict__ bmem,
    const float* __restrict__ Wout, const float* __restrict__ bout,
    float* __restrict__ out) {
  __shared__ __align__(16) float xl[HIDN];
  __shared__ float ul[NMEM];
  const int b = blockIdx.x, t = threadIdx.x;
  xl[t]       = xc[b * HIDN + t] * (1.0f / NCLUST);
  xl[t + 128] = xc[b * HIDN + t + 128] * (1.0f / NCLUST);
  __syncthreads();
  float a = 0.0f;
  const float4* wr2 = (const float4*)(Wmem + (size_t)t * HIDN);
#pragma unroll 4
  for (int q = 0; q < HIDN / 4; ++q) {
    const float4 wv = wr2[q];
    const float4 xv = *(const float4*)&xl[q * 4];
    a = fmaf(wv.x, xv.x, a); a = fmaf(wv.y, xv.y, a);
    a = fmaf(wv.z, xv.z, a); a = fmaf(wv.w, xv.w, a);
  }
  a += bmem[t] + memory[b * NMEM + t];
  a = fmaxf(a, 0.0f);
  ul[t] = a;
  out[NB * NCLS + b * NMEM + t] = a;
  __syncthreads();
  if (t < NCLS) {
    float o = 0.0f;
#pragma unroll 4
    for (int m = 0; m < NMEM; ++m) o = fmaf(ul[m], Wout[t * NMEM + m], o);
    out[b * NCLS + t] = o + bout[t];
  }
}

// ---------------- launcher ----------------
extern "C" void kernel_launch(void* const* d_in, const int* in_sizes, int n_in,
                              void* d_out, int out_size, void* d_ws, size_t ws_size,
                              hipStream_t stream) {
  (void)in_sizes; (void)n_in; (void)out_size; (void)ws_size;
  const float* x    = (const float*)d_in[0];
  const float* mem  = (const float*)d_in[1];
  const float* Wfc  = (const float*)d_in[2];
  const float* bfc  = (const float*)d_in[3];
  const float* Wmem = (const float*)d_in[4];
  const float* bmem = (const float*)d_in[5];
  const float* Wout = (const float*)d_in[6];
  const float* bout = (const float*)d_in[7];
  float* out = (float*)d_out;

  char* ws = (char*)d_ws;
  size_t off = 0;
  ull* keys = (ull*)(ws + off);          off += (size_t)NB * NS * 8;      // 2 MiB
  unsigned int* topk = (unsigned int*)(ws + off); off += (size_t)NB * KTOP * 4;
  float* xc = (float*)(ws + off);        off += (size_t)NB * HIDN * 4;
  unsigned short* Wbf = (unsigned short*)(ws + off); off += (size_t)HIDN * CIN * 2;
  ull* maskw = (ull*)(ws + off);         // 1 MiB (131072 u64 words)

  norms_kernel<<<dim3(NORM_BLOCKS + WPREP_BLOCKS + MASK_BLOCKS), 256, 0,
                 stream>>>(x, keys, xc, Wfc, Wbf, maskw);
  sortA_kernel<<<dim3(NB * 2), 512, 0, stream>>>(keys);
  sortB_kernel<<<dim3(NB), 512, 0, stream>>>(keys, topk);
  gemm_kernel<<<dim3(1024), 256, 0, stream>>>(x, Wbf, bfc, topk, maskw, xc);
  tail_kernel<<<dim3(NB), 128, 0, stream>>>(xc, mem, Wmem, bmem, Wout, bout, out);
}